// Round 7
// baseline (724.904 us; speedup 1.0000x reference)
//
#include <hip/hip_runtime.h>
#include <hip/hip_bf16.h>

typedef __attribute__((ext_vector_type(4))) int i32x4;
typedef __attribute__((ext_vector_type(8))) int i32x8;
typedef __attribute__((ext_vector_type(16))) float f32x16;

// exact floor(log2(x)) for x > 0 (handles subnormals)
__device__ __forceinline__ int flog2(float x) {
  unsigned u = __float_as_uint(x);
  int e = (int)((u >> 23) & 255u);
  if (e) return e - 127;
  unsigned m = u & 0x7fffffu;
  return (31 - __clz(m)) - 149;
}

// exact 2^e for e in [-252, 254]
__device__ __forceinline__ float exp2i(int e) {
  int e1 = e >> 1, e2 = e - e1;
  return __uint_as_float((unsigned)(e1 + 127) << 23) *
         __uint_as_float((unsigned)(e2 + 127) << 23);
}

// quantize y (already divided by shared scale) to e2m<MFRAC>, round-half-even, saturate
template <int MFRAC>
__device__ __forceinline__ float qelem(float y, float maxn) {
  float ay = fabsf(y);
  int e = (ay == 0.f) ? 0 : flog2(ay);
  if (e < 0) e = 0;  // min_exp = 0 for ebits=2
  float r = rintf(y * exp2i(MFRAC - e)) * exp2i(e - MFRAC);
  return fminf(fmaxf(r, -maxn), maxn);
}

// general RNE fp32 -> OCP e4m3 encode (|v| <= 448; exact on our folded value grid)
__device__ __forceinline__ unsigned char enc_rne(float v) {
  unsigned u = __float_as_uint(v);
  unsigned s = u >> 31;
  float a = fabsf(v);
  if (a == 0.f) return (unsigned char)(s << 7);
  int e = flog2(a);
  if (e < -6) e = -6;                      // subnormal regime
  int qi = (int)rintf(a * exp2i(3 - e));   // RNE to 3-frac-bit grid -> [0,16]
  if (qi == 0) return (unsigned char)(s << 7);
  if (qi == 16) { qi = 8; e += 1; }
  unsigned exf, m;
  if (qi < 8) { exf = 0u; m = (unsigned)qi; }          // e == -6 subnormal
  else { exf = (unsigned)(e + 7); m = (unsigned)(qi - 8); }
  return (unsigned char)((s << 7) | (exf << 3) | m);
}

__device__ __forceinline__ void gl_lds16(const unsigned char* g, unsigned char* l) {
  __builtin_amdgcn_global_load_lds(
      (const __attribute__((address_space(1))) void*)g,
      (__attribute__((address_space(3))) void*)l, 16, 0, 0);
}

template <int N>
__device__ __forceinline__ void vmw() {
  if constexpr (N == 4) asm volatile("s_waitcnt vmcnt(4)" ::: "memory");
  else asm volatile("s_waitcnt vmcnt(0)" ::: "memory");
}

// ------ MX quantization with exponent folding: fp32 -> e4m3 byte = q * 2^(se - se0) ---
// lane handles 4 consecutive floats; 8 lanes = one 32-elem MX block.
// q = e2m<MFRAC> quantization of (x / 2^se); folding is exact for se - se0 in [-6, 5].
template <int MFRAC, int EMAX>
__global__ void quant_fold(const float* __restrict__ in, unsigned char* __restrict__ out,
                           long n4, float maxn, int se0) {
  long i = (long)blockIdx.x * blockDim.x + threadIdx.x;
  long stride = (long)gridDim.x * blockDim.x;
  for (; i < n4; i += stride) {
    float4 v = reinterpret_cast<const float4*>(in)[i];
    float am = fmaxf(fmaxf(fabsf(v.x), fabsf(v.y)), fmaxf(fabsf(v.z), fabsf(v.w)));
    am = fmaxf(am, __shfl_xor(am, 1));
    am = fmaxf(am, __shfl_xor(am, 2));
    am = fmaxf(am, __shfl_xor(am, 4));
    int se = ((am == 0.f) ? 0 : flog2(am)) - EMAX;
    se = se < -127 ? -127 : (se > 127 ? 127 : se);
    float inv = exp2i(-se), f = exp2i(se - se0);
    unsigned o = (unsigned)enc_rne(qelem<MFRAC>(v.x * inv, maxn) * f)
               | ((unsigned)enc_rne(qelem<MFRAC>(v.y * inv, maxn) * f) << 8)
               | ((unsigned)enc_rne(qelem<MFRAC>(v.z * inv, maxn) * f) << 16)
               | ((unsigned)enc_rne(qelem<MFRAC>(v.w * inv, maxn) * f) << 24);
    reinterpret_cast<unsigned*>(out)[i] = o;
  }
}

// LDS fragment layout: [subtile(32 rows)][half j][lane][16B]; lane's 32B = K-contiguous
__device__ __forceinline__ i32x8 ld_frag(const unsigned char* p) {
  i32x4 lo = *reinterpret_cast<const i32x4*>(p);
  i32x4 hi = *reinterpret_cast<const i32x4*>(p + 1024);
  i32x8 r;
  r[0] = lo[0]; r[1] = lo[1]; r[2] = lo[2]; r[3] = lo[3];
  r[4] = hi[0]; r[5] = hi[1]; r[6] = hi[2]; r[7] = hi[3];
  return r;
}

// ----- fp8 GEMM, 128x128 tile, BK=64, 4 waves, dbuf + COUNTED vmcnt (T3/T4) ---------
// All HW scale bytes = 1.0 (0x7f7f7f7f): convention-immune, full MX instruction rate.
// A: [M][K] e4m3 (folded), B: [N][K] (B^T form, pre-offset). True product = acc * fac.
// Grid is 1D, nwg % 8 == 0; XCD-bijective swizzle; NBX = 32 (M/128) fixed.
// EPI=0: Cf[row*ldC + c0 + col] = acc * fac
// EPI=1: v = silu(gate[row*N+col]) * (acc*fac); fp6-MX quant along 32-col blocks;
//        C8[row*ldC + c0 + col] = e4m3(q * 2^(se - se0out))
template <int EPI>
__global__ __launch_bounds__(256) void mx_gemm(
    const unsigned char* __restrict__ A, const unsigned char* __restrict__ B,
    float* __restrict__ Cf, const float* __restrict__ gate,
    unsigned char* __restrict__ C8,
    int N, int K, int ldC, int c0, float fac, int se0out) {
  __shared__ __align__(16) unsigned char lds[2][16384];  // [buf][A:0..8191 | B:8192..]
  const int t = threadIdx.x, l = t & 63, w = t >> 6;
  const int wm = w >> 1, wn = w & 1;
  const int lr = l & 31, lg = l >> 5;
  // XCD-aware bijective swizzle (T1): consecutive swz on one XCD share the B-strip
  const int nwg = (int)gridDim.x;
  const int swz = ((int)blockIdx.x & 7) * (nwg >> 3) + ((int)blockIdx.x >> 3);
  const int rowA = (swz & 31) * 128;
  const int rowB = (swz >> 5) * 128;
  const int SCL = 0x7f7f7f7f;  // e8m0 1.0 in every byte: any byte/lane selection = no-op

  f32x16 acc[2][2];
#pragma unroll
  for (int i = 0; i < 2; ++i)
#pragma unroll
    for (int j = 0; j < 2; ++j) acc[i][j] = (f32x16)(0.f);

  // staging: 16 chunks (8 A + 8 B) of 1KB per K-step; wave w owns chunks {w,w+4,w+8,w+12}
  const unsigned char* srcp[4];
  int dstoff[4];
#pragma unroll
  for (int idx = 0; idx < 4; ++idx) {
    int c = w + idx * 4;
    int isA = (c < 8) ? 1 : 0;
    int sub = (c & 7) >> 1, j = c & 1;
    srcp[idx] = (isA ? A + (size_t)(rowA + sub * 32 + lr) * K
                     : B + (size_t)(rowB + sub * 32 + lr) * K) + lg * 32 + j * 16;
    dstoff[idx] = (isA ? 0 : 8192) + sub * 2048 + j * 1024 + l * 16;
  }

  auto stage = [&](int wb) {  // advance to next tile, issue 4 loads into buffer wb
#pragma unroll
    for (int idx = 0; idx < 4; ++idx) {
      srcp[idx] += 64;
      gl_lds16(srcp[idx], &lds[wb][dstoff[idx]]);
    }
  };
  auto compute = [&](int rb) {  // one K-step from buffer rb (T5: setprio around MFMAs)
    const unsigned char* pA = &lds[rb][0];
    const unsigned char* pB = &lds[rb][8192];
    i32x8 af0 = ld_frag(pA + (2 * wm + 0) * 2048 + l * 16);
    i32x8 af1 = ld_frag(pA + (2 * wm + 1) * 2048 + l * 16);
    i32x8 bf0 = ld_frag(pB + (2 * wn + 0) * 2048 + l * 16);
    i32x8 bf1 = ld_frag(pB + (2 * wn + 1) * 2048 + l * 16);
    __builtin_amdgcn_s_setprio(1);
    acc[0][0] = __builtin_amdgcn_mfma_scale_f32_32x32x64_f8f6f4(af0, bf0, acc[0][0], 0, 0, 0, SCL, 0, SCL);
    acc[0][1] = __builtin_amdgcn_mfma_scale_f32_32x32x64_f8f6f4(af0, bf1, acc[0][1], 0, 0, 0, SCL, 0, SCL);
    acc[1][0] = __builtin_amdgcn_mfma_scale_f32_32x32x64_f8f6f4(af1, bf0, acc[1][0], 0, 0, 0, SCL, 0, SCL);
    acc[1][1] = __builtin_amdgcn_mfma_scale_f32_32x32x64_f8f6f4(af1, bf1, acc[1][1], 0, 0, 0, SCL, 0, SCL);
    __builtin_amdgcn_s_setprio(0);
  };

  const int nt = K >> 6;  // 32 (gate/up) or 128 (down): always even
  // prologue: stage tile 0 into buf 0 (no advance)
#pragma unroll
  for (int idx = 0; idx < 4; ++idx) gl_lds16(srcp[idx], &lds[0][dstoff[idx]]);

  // Per tile: stage(next) -> vmcnt(4) [own current-tile loads landed; next's stay in
  // flight ACROSS the barrier] -> barrier [publishes to all waves] -> compute ->
  // barrier [all waves done reading; safe to overwrite next half-iter].
  for (int tt = 0; tt < nt; tt += 2) {
    if (tt + 1 < nt) { stage(1); vmw<4>(); } else vmw<0>();
    __builtin_amdgcn_s_barrier();
    __builtin_amdgcn_sched_barrier(0);
    compute(0);
    __builtin_amdgcn_s_barrier();
    if (tt + 2 < nt) { stage(0); vmw<4>(); } else vmw<0>();
    __builtin_amdgcn_s_barrier();
    __builtin_amdgcn_sched_barrier(0);
    compute(1);
    __builtin_amdgcn_s_barrier();
  }

  // 32x32 C/D layout: col = lane&31, row = (reg&3) + 8*(reg>>2) + 4*(lane>>5)
  if (EPI == 0) {
#pragma unroll
    for (int i = 0; i < 2; ++i)
#pragma unroll
      for (int j = 0; j < 2; ++j)
#pragma unroll
        for (int r = 0; r < 16; ++r) {
          int row = rowA + (2 * wm + i) * 32 + (r & 3) + 8 * (r >> 2) + 4 * lg;
          int col = rowB + (2 * wn + j) * 32 + lr;
          Cf[(size_t)row * ldC + c0 + col] = acc[i][j][r] * fac;
        }
  } else {
#pragma unroll
    for (int i = 0; i < 2; ++i)
#pragma unroll
      for (int j = 0; j < 2; ++j)
#pragma unroll
        for (int r = 0; r < 16; ++r) {
          int row = rowA + (2 * wm + i) * 32 + (r & 3) + 8 * (r >> 2) + 4 * lg;
          int col = rowB + (2 * wn + j) * 32 + lr;
          float u = acc[i][j][r] * fac;
          float g = gate[(size_t)row * N + col];
          float v = u * (g / (1.f + expf(-g)));
          float am = fabsf(v);
          am = fmaxf(am, __shfl_xor(am, 1));
          am = fmaxf(am, __shfl_xor(am, 2));
          am = fmaxf(am, __shfl_xor(am, 4));
          am = fmaxf(am, __shfl_xor(am, 8));
          am = fmaxf(am, __shfl_xor(am, 16));
          int se = ((am == 0.f) ? 0 : flog2(am)) - 2;
          se = se < -127 ? -127 : (se > 127 ? 127 : se);
          float y = qelem<3>(v * exp2i(-se), 7.5f);
          C8[(size_t)row * ldC + c0 + col] = enc_rne(y * exp2i(se - se0out));
        }
  }
}

extern "C" void kernel_launch(void* const* d_in, const int* in_sizes, int n_in,
                              void* d_out, int out_size, void* d_ws, size_t ws_size,
                              hipStream_t stream) {
  const float* x = (const float*)d_in[0];
  const float* wg = (const float*)d_in[1];
  const float* wu = (const float*)d_in[2];
  const float* wd = (const float*)d_in[3];
  float* out = (float*)d_out;

  const int S = 4096, H = 2048, I = 8192;

  // per-tensor fold baselines: exact while block se in [se0-6, se0+5]
  const int SE0X = -1, SE0W = -7, SE0I = -2;
  const float FAC_GU = 0.00390625f;     // 2^(SE0X + SE0W) = 2^-8
  const float FAC_DN = 0.001953125f;    // 2^(SE0I + SE0W) = 2^-9

  unsigned char* p = (unsigned char*)d_ws;
  unsigned char* xq8 = p;  p += (size_t)S * H;   //  8.4 MB
  unsigned char* wgq8 = p; p += (size_t)I * H;   // 16.8 MB
  unsigned char* wuq8 = p; p += (size_t)I * H;   // 16.8 MB
  unsigned char* wdq8 = p; p += (size_t)H * I;   // 16.8 MB
  unsigned char* iq8 = p;  p += (size_t)S * I;   // 33.6 MB
  size_t base_bytes = (size_t)(p - (unsigned char*)d_ws);  // ~92 MB
  float* gatef = (float*)p;

  // quantize: act fp6 e2m3 (mfrac=3, emax=2, maxn=7.5); weights fp4 e2m1 (1, 2, 6.0)
  quant_fold<3, 2><<<2048, 256, 0, stream>>>(x, xq8, (long)S * H / 4, 7.5f, SE0X);
  quant_fold<1, 2><<<2048, 256, 0, stream>>>(wg, wgq8, (long)I * H / 4, 6.0f, SE0W);
  quant_fold<1, 2><<<2048, 256, 0, stream>>>(wu, wuq8, (long)I * H / 4, 6.0f, SE0W);
  quant_fold<1, 2><<<2048, 256, 0, stream>>>(wd, wdq8, (long)H * I / 4, 6.0f, SE0W);

  // largest power-of-two column chunk W with S*W*4 bytes of fp32 gate fitting
  size_t avail = ws_size > base_bytes ? ws_size - base_bytes : 0;
  int W = 128;
  for (int cand = I; cand >= 128; cand >>= 1)
    if ((size_t)S * cand * 4 <= avail) { W = cand; break; }

  for (int c0 = 0; c0 < I; c0 += W) {
    // gate chunk -> fp32 gatef [S][W]   (grid = 32 * (W/128), % 8 == 0)
    mx_gemm<0><<<(S / 128) * (W / 128), 256, 0, stream>>>(
        xq8, wgq8 + (size_t)c0 * H, gatef, nullptr, nullptr,
        W, H, W, 0, FAC_GU, 0);
    // up chunk + SwiGLU + fp6-MX requant (folded) -> iq8 columns [c0, c0+W)
    mx_gemm<1><<<(S / 128) * (W / 128), 256, 0, stream>>>(
        xq8, wuq8 + (size_t)c0 * H, nullptr, gatef, iq8,
        W, H, I, c0, FAC_GU, SE0I);
  }

  // down GEMM -> out [S][H] fp32   (grid = 32 * 16 = 512)
  mx_gemm<0><<<(S / 128) * (H / 128), 256, 0, stream>>>(
      iq8, wdq8, out, nullptr, nullptr, H, I, H, 0, FAC_DN, 0);
}

// Round 9
// 663.096 us; speedup vs baseline: 1.0932x; 1.0932x over previous
//
#include <hip/hip_runtime.h>
#include <hip/hip_bf16.h>

typedef __attribute__((ext_vector_type(4))) int i32x4;
typedef __attribute__((ext_vector_type(8))) int i32x8;
typedef __attribute__((ext_vector_type(16))) float f32x16;

// exact floor(log2(x)) for x > 0 (handles subnormals)
__device__ __forceinline__ int flog2(float x) {
  unsigned u = __float_as_uint(x);
  int e = (int)((u >> 23) & 255u);
  if (e) return e - 127;
  unsigned m = u & 0x7fffffu;
  return (31 - __clz(m)) - 149;
}

// exact 2^e for e in [-252, 254]
__device__ __forceinline__ float exp2i(int e) {
  int e1 = e >> 1, e2 = e - e1;
  return __uint_as_float((unsigned)(e1 + 127) << 23) *
         __uint_as_float((unsigned)(e2 + 127) << 23);
}

// quantize y (already divided by shared scale) to e2m<MFRAC>, round-half-even, saturate
template <int MFRAC>
__device__ __forceinline__ float qelem(float y, float maxn) {
  float ay = fabsf(y);
  int e = (ay == 0.f) ? 0 : flog2(ay);
  if (e < 0) e = 0;  // min_exp = 0 for ebits=2
  float r = rintf(y * exp2i(MFRAC - e)) * exp2i(e - MFRAC);
  return fminf(fmaxf(r, -maxn), maxn);
}

// general RNE fp32 -> OCP e4m3 encode (|v| <= 448; exact on our folded value grid)
__device__ __forceinline__ unsigned char enc_rne(float v) {
  unsigned u = __float_as_uint(v);
  unsigned s = u >> 31;
  float a = fabsf(v);
  if (a == 0.f) return (unsigned char)(s << 7);
  int e = flog2(a);
  if (e < -6) e = -6;                      // subnormal regime
  int qi = (int)rintf(a * exp2i(3 - e));   // RNE to 3-frac-bit grid -> [0,16]
  if (qi == 0) return (unsigned char)(s << 7);
  if (qi == 16) { qi = 8; e += 1; }
  unsigned exf, m;
  if (qi < 8) { exf = 0u; m = (unsigned)qi; }          // e == -6 subnormal
  else { exf = (unsigned)(e + 7); m = (unsigned)(qi - 8); }
  return (unsigned char)((s << 7) | (exf << 3) | m);
}

__device__ __forceinline__ void gl_lds16(const unsigned char* g, unsigned char* l) {
  __builtin_amdgcn_global_load_lds(
      (const __attribute__((address_space(1))) void*)g,
      (__attribute__((address_space(3))) void*)l, 16, 0, 0);
}

template <int N>
__device__ __forceinline__ void vmw() {
  if constexpr (N == 4) asm volatile("s_waitcnt vmcnt(4)" ::: "memory");
  else asm volatile("s_waitcnt vmcnt(0)" ::: "memory");
}

// ------ MX quantization with exponent folding: fp32 -> e4m3 byte = q * 2^(se - se0) ---
template <int MFRAC, int EMAX>
__global__ void quant_fold(const float* __restrict__ in, unsigned char* __restrict__ out,
                           long n4, float maxn, int se0) {
  long i = (long)blockIdx.x * blockDim.x + threadIdx.x;
  long stride = (long)gridDim.x * blockDim.x;
  for (; i < n4; i += stride) {
    float4 v = reinterpret_cast<const float4*>(in)[i];
    float am = fmaxf(fmaxf(fabsf(v.x), fabsf(v.y)), fmaxf(fabsf(v.z), fabsf(v.w)));
    am = fmaxf(am, __shfl_xor(am, 1));
    am = fmaxf(am, __shfl_xor(am, 2));
    am = fmaxf(am, __shfl_xor(am, 4));
    int se = ((am == 0.f) ? 0 : flog2(am)) - EMAX;
    se = se < -127 ? -127 : (se > 127 ? 127 : se);
    float inv = exp2i(-se), f = exp2i(se - se0);
    unsigned o = (unsigned)enc_rne(qelem<MFRAC>(v.x * inv, maxn) * f)
               | ((unsigned)enc_rne(qelem<MFRAC>(v.y * inv, maxn) * f) << 8)
               | ((unsigned)enc_rne(qelem<MFRAC>(v.z * inv, maxn) * f) << 16)
               | ((unsigned)enc_rne(qelem<MFRAC>(v.w * inv, maxn) * f) << 24);
    reinterpret_cast<unsigned*>(out)[i] = o;
  }
}

// LDS subtile (32 rows x 64 K-bytes = 2KB): [j:2][lane:64][16B]; lane's 32B K-contiguous
__device__ __forceinline__ i32x8 ld_frag(const unsigned char* p) {
  i32x4 lo = *reinterpret_cast<const i32x4*>(p);
  i32x4 hi = *reinterpret_cast<const i32x4*>(p + 1024);
  i32x8 r;
  r[0] = lo[0]; r[1] = lo[1]; r[2] = lo[2]; r[3] = lo[3];
  r[4] = hi[0]; r[5] = hi[1]; r[6] = hi[2]; r[7] = hi[3];
  return r;
}

// ----- fp8 GEMM, 256x256 tile, BK=64, 8 waves (2x4; wave owns 128x64 = 4x2 accs) ----
// All HW scale bytes = 1.0 (0x7f7f7f7f): convention-immune, full MX instruction rate.
// A: [*][lda] e4m3 (folded), B: [*][ldb] (B^T form, pre-offset). Product = acc * fac.
// Grid = KS * 16 * nby (1D): bx=n%16 (A strip), by=(n/16)%nby (B strip), ks=n/(16*nby).
// EPI=0: (ks==0 ? Cf : Cf2)[row*ldC + c0 + col] = acc * fac
// EPI=1: v = silu(gate[row*N+col]) * (acc*fac); fp6-MX quant along 32-col blocks
template <int EPI>
__global__ __launch_bounds__(512, 2) void mx_gemm(
    const unsigned char* __restrict__ A, int lda,
    const unsigned char* __restrict__ B, int ldb,
    float* __restrict__ Cf, float* __restrict__ Cf2,
    const float* __restrict__ gate, unsigned char* __restrict__ C8,
    int N, int K, int ldC, int c0, float fac, int se0out, int nby) {
  __shared__ __align__(16) unsigned char lds[2][32768];  // [buf][A:0..16383 | B:16384..]
  const int t = threadIdx.x, l = t & 63, w = t >> 6;
  const int wr = w >> 2, wc = w & 3;          // 2x4 wave grid; wave tile 128x64
  const int lr = l & 31, lg = l >> 5;
  const int n = (int)blockIdx.x;
  const int bx = n & 15, by = (n >> 4) % nby, ks = n / (16 * nby);
  const int rowA = bx * 256, rowB = by * 256;
  const int k0 = ks * K;
  const int SCL = 0x7f7f7f7f;  // e8m0 1.0 in every byte: scale path is a no-op

  f32x16 acc[4][2];
#pragma unroll
  for (int i = 0; i < 4; ++i)
#pragma unroll
    for (int j = 0; j < 2; ++j) acc[i][j] = (f32x16)(0.f);

  // staging: 32 chunks of 1KB (16 A + 16 B) per K-step; wave w owns {w, w+8, w+16, w+24}
  const unsigned char* srcp[4];
  int dstoff[4];
#pragma unroll
  for (int idx = 0; idx < 4; ++idx) {
    int c = w + idx * 8;
    int isA = (c < 16) ? 1 : 0;
    int sub = (c >> 1) & 7, j = c & 1;
    srcp[idx] = (isA ? A + (size_t)(rowA + sub * 32 + lr) * lda
                     : B + (size_t)(rowB + sub * 32 + lr) * ldb) + k0 + lg * 32 + j * 16;
    dstoff[idx] = (isA ? 0 : 16384) + sub * 2048 + j * 1024 + l * 16;
  }

  auto stage = [&](int wb) {  // advance to next tile, issue 4 loads into buffer wb
#pragma unroll
    for (int idx = 0; idx < 4; ++idx) {
      srcp[idx] += 64;
      gl_lds16(srcp[idx], &lds[wb][dstoff[idx]]);
    }
  };
  auto compute = [&](int rb) {  // one K-step: 8 MFMAs from buffer rb
    const unsigned char* pA = &lds[rb][0];
    const unsigned char* pB = &lds[rb][16384];
    i32x8 af[4], bf[2];
#pragma unroll
    for (int m = 0; m < 4; ++m) af[m] = ld_frag(pA + (wr * 4 + m) * 2048 + l * 16);
#pragma unroll
    for (int nn = 0; nn < 2; ++nn) bf[nn] = ld_frag(pB + (wc * 2 + nn) * 2048 + l * 16);
    __builtin_amdgcn_s_setprio(1);
#pragma unroll
    for (int m = 0; m < 4; ++m)
#pragma unroll
      for (int nn = 0; nn < 2; ++nn)
        acc[m][nn] = __builtin_amdgcn_mfma_scale_f32_32x32x64_f8f6f4(
            af[m], bf[nn], acc[m][nn], 0, 0, 0, SCL, 0, SCL);
    __builtin_amdgcn_s_setprio(0);
  };

  const int nt = K >> 6;  // 32 (gate/up, K=2048) or 64 (down halves, K=4096): even
  // prologue: stage tile 0 into buf 0 (no advance)
#pragma unroll
  for (int idx = 0; idx < 4; ++idx) gl_lds16(srcp[idx], &lds[0][dstoff[idx]]);

  // counted-vmcnt 2-phase: stage(next) -> vmcnt(4) (current landed, next in flight
  // across the barrier) -> barrier -> compute -> barrier
  for (int tt = 0; tt < nt; tt += 2) {
    if (tt + 1 < nt) { stage(1); vmw<4>(); } else vmw<0>();
    __builtin_amdgcn_s_barrier();
    __builtin_amdgcn_sched_barrier(0);
    compute(0);
    __builtin_amdgcn_s_barrier();
    if (tt + 2 < nt) { stage(0); vmw<4>(); } else vmw<0>();
    __builtin_amdgcn_s_barrier();
    __builtin_amdgcn_sched_barrier(0);
    compute(1);
    __builtin_amdgcn_s_barrier();
  }

  // 32x32 C/D layout: col = lane&31, row = (reg&3) + 8*(reg>>2) + 4*(lane>>5)
  if (EPI == 0) {
    float* D = ks ? Cf2 : Cf;
#pragma unroll
    for (int m = 0; m < 4; ++m)
#pragma unroll
      for (int nn = 0; nn < 2; ++nn)
#pragma unroll
        for (int r = 0; r < 16; ++r) {
          int row = rowA + wr * 128 + m * 32 + (r & 3) + 8 * (r >> 2) + 4 * lg;
          int col = rowB + wc * 64 + nn * 32 + lr;
          D[(size_t)row * ldC + c0 + col] = acc[m][nn][r] * fac;
        }
  } else {
#pragma unroll
    for (int m = 0; m < 4; ++m)
#pragma unroll
      for (int nn = 0; nn < 2; ++nn)
#pragma unroll
        for (int r = 0; r < 16; ++r) {
          int row = rowA + wr * 128 + m * 32 + (r & 3) + 8 * (r >> 2) + 4 * lg;
          int col = rowB + wc * 64 + nn * 32 + lr;
          float u = acc[m][nn][r] * fac;
          float g = gate[(size_t)row * N + col];
          float v = u * (g / (1.f + expf(-g)));
          float am = fabsf(v);
          am = fmaxf(am, __shfl_xor(am, 1));
          am = fmaxf(am, __shfl_xor(am, 2));
          am = fmaxf(am, __shfl_xor(am, 4));
          am = fmaxf(am, __shfl_xor(am, 8));
          am = fmaxf(am, __shfl_xor(am, 16));
          int se = ((am == 0.f) ? 0 : flog2(am)) - 2;
          se = se < -127 ? -127 : (se > 127 ? 127 : se);
          float y = qelem<3>(v * exp2i(-se), 7.5f);
          C8[(size_t)row * ldC + c0 + col] = enc_rne(y * exp2i(se - se0out));
        }
  }
}

__global__ void add_f32(float* __restrict__ out, const float* __restrict__ part, long n4) {
  long i = (long)blockIdx.x * blockDim.x + threadIdx.x;
  long stride = (long)gridDim.x * blockDim.x;
  for (; i < n4; i += stride) {
    float4 a = reinterpret_cast<float4*>(out)[i];
    float4 b = reinterpret_cast<const float4*>(part)[i];
    a.x += b.x; a.y += b.y; a.z += b.z; a.w += b.w;
    reinterpret_cast<float4*>(out)[i] = a;
  }
}

extern "C" void kernel_launch(void* const* d_in, const int* in_sizes, int n_in,
                              void* d_out, int out_size, void* d_ws, size_t ws_size,
                              hipStream_t stream) {
  const float* x = (const float*)d_in[0];
  const float* wg = (const float*)d_in[1];
  const float* wu = (const float*)d_in[2];
  const float* wd = (const float*)d_in[3];
  float* out = (float*)d_out;

  const int S = 4096, H = 2048, I = 8192;

  // per-tensor fold baselines: exact while block se in [se0-6, se0+5]
  const int SE0X = -1, SE0W = -7, SE0I = -2;
  const float FAC_GU = 0.00390625f;     // 2^(SE0X + SE0W) = 2^-8
  const float FAC_DN = 0.001953125f;    // 2^(SE0I + SE0W) = 2^-9

  unsigned char* p = (unsigned char*)d_ws;
  unsigned char* xq8 = p;  p += (size_t)S * H;   //  8.4 MB
  unsigned char* wgq8 = p; p += (size_t)I * H;   // 16.8 MB
  unsigned char* wuq8 = p; p += (size_t)I * H;   // 16.8 MB
  unsigned char* wdq8 = p; p += (size_t)H * I;   // 16.8 MB
  unsigned char* iq8 = p;  p += (size_t)S * I;   // 33.6 MB
  size_t base_bytes = (size_t)(p - (unsigned char*)d_ws);  // ~92 MB
  float* gatef = (float*)p;          // chunked fp32 gate buffer (>= 64 MB available)
  float* pf = (float*)p;             // down-GEMM K-split partial (reuses dead gatef)

  // quantize: act fp6 e2m3 (mfrac=3, emax=2, maxn=7.5); weights fp4 e2m1 (1, 2, 6.0)
  quant_fold<3, 2><<<2048, 256, 0, stream>>>(x, xq8, (long)S * H / 4, 7.5f, SE0X);
  quant_fold<1, 2><<<2048, 256, 0, stream>>>(wg, wgq8, (long)I * H / 4, 6.0f, SE0W);
  quant_fold<1, 2><<<2048, 256, 0, stream>>>(wu, wuq8, (long)I * H / 4, 6.0f, SE0W);
  quant_fold<1, 2><<<2048, 256, 0, stream>>>(wd, wdq8, (long)H * I / 4, 6.0f, SE0W);

  // largest column chunk W (multiple of 256, pow2) with S*W*4 fp32 gate fitting
  size_t avail = ws_size > base_bytes ? ws_size - base_bytes : 0;
  int W = 4096;  // guaranteed: ws_size >= 176MB (Round-0 proven) -> avail >= 84MB
  if ((size_t)S * 8192 * 4 <= avail) W = 8192;

  for (int c0 = 0; c0 < I; c0 += W) {
    int nby = W / 256;
    // gate chunk -> fp32 gatef [S][W]
    mx_gemm<0><<<16 * nby, 512, 0, stream>>>(
        xq8, H, wgq8 + (size_t)c0 * H, H, gatef, nullptr, nullptr, nullptr,
        W, H, W, 0, FAC_GU, 0, nby);
    // up chunk + SwiGLU + fp6-MX requant (folded) -> iq8 columns [c0, c0+W)
    mx_gemm<1><<<16 * nby, 512, 0, stream>>>(
        xq8, H, wuq8 + (size_t)c0 * H, H, nullptr, nullptr, gatef, iq8,
        I, H, I, c0, FAC_GU, SE0I, nby);
  }

  // down GEMM, K split in 2 (grid 2*16*8 = 256): ks=0 -> out, ks=1 -> pf; then add
  mx_gemm<0><<<2 * 16 * (H / 256), 512, 0, stream>>>(
      iq8, I, wdq8, I, out, pf, nullptr, nullptr,
      H, I / 2, H, 0, FAC_DN, 0, H / 256);
  add_f32<<<2048, 256, 0, stream>>>(out, pf, (long)S * H / 4);
}